// Round 1
// baseline (494.558 us; speedup 1.0000x reference)
//
#include <hip/hip_runtime.h>
#include <hip/hip_bf16.h>
#include <float.h>

#define NTOK   2048
#define VOCAB  32000
#define DIM    512
#define NCHUNK 16
#define VCHUNK (VOCAB / NCHUNK)   // 2000
#define VSTEP  16
#define NSTEPS (VCHUNK / VSTEP)   // 125
#define ROWSB  64
#define NRB    (NTOK / ROWSB)     // 32

typedef __attribute__((ext_vector_type(4))) float  f32x4;
typedef __attribute__((ext_vector_type(8))) short  bf16x8;
typedef __attribute__((ext_vector_type(4))) short  bf16x4;

__device__ __forceinline__ short f2bf(float f) {
    unsigned u = __builtin_bit_cast(unsigned, f);
    u = (u + 0x7FFFu + ((u >> 16) & 1u)) >> 16;   // RNE to bf16
    return (short)u;
}

__global__ void init_out(float* out) {
    if (threadIdx.x < 2) out[threadIdx.x] = 0.f;
}

// e2[v] = sum_k emb[v][k]^2  (one wave per vocab row)
__global__ __launch_bounds__(256) void e2_kernel(const float* __restrict__ emb,
                                                 float* __restrict__ e2) {
    int gid = blockIdx.x * 256 + threadIdx.x;
    int wid = gid >> 6;
    int l   = gid & 63;
    if (wid >= VOCAB) return;
    const float* row = emb + (size_t)wid * DIM + l * 8;
    f32x4 a = *(const f32x4*)row;
    f32x4 b = *(const f32x4*)(row + 4);
    float s = a.x*a.x + a.y*a.y + a.z*a.z + a.w*a.w
            + b.x*b.x + b.y*b.y + b.z*b.z + b.w*b.w;
    #pragma unroll
    for (int m = 1; m < 64; m <<= 1) s += __shfl_xor(s, m);
    if (l == 0) e2[wid] = s;
}

// Fused: bf16 MFMA dot(g_row, emb_v) -> dist -> online softmax partials
// grid (NCHUNK, NRB), block 256 (4 waves x 16 rows each)
__global__ __launch_bounds__(256) void fused_kernel(
    const float* __restrict__ pred_ll, const int* __restrict__ target,
    const float* __restrict__ emb, const float* __restrict__ e2,
    float* __restrict__ partials /* [NTOK][NCHUNK][3] */) {

    const int bx = blockIdx.x;           // v-chunk
    const int by = blockIdx.y;           // row block
    const int t  = threadIdx.x;
    const int w  = t >> 6;
    const int l  = t & 63;
    const int l15 = l & 15;
    const int lg  = l >> 4;              // 0..3

    __shared__ short ldsb[16 * DIM];     // 16 KB bf16 B-tile, XOR-swizzled rows

    const int rowbase = by * ROWSB + w * 16;

    // ---- A fragments: 16 gold-embedding rows per wave, resident in regs ----
    // MFMA A layout: lane l supplies A[l&15][k = (l>>4)*8 + j], j=0..7
    bf16x8 afrag[16];
    {
        const int grow = target[rowbase + l15];
        const float* gsrc = emb + (size_t)grow * DIM;
        #pragma unroll
        for (int ks = 0; ks < 16; ++ks) {
            const int k0 = ks * 32 + lg * 8;
            f32x4 x0 = *(const f32x4*)(gsrc + k0);
            f32x4 x1 = *(const f32x4*)(gsrc + k0 + 4);
            bf16x8 a;
            a[0] = f2bf(x0.x); a[1] = f2bf(x0.y); a[2] = f2bf(x0.z); a[3] = f2bf(x0.w);
            a[4] = f2bf(x1.x); a[5] = f2bf(x1.y); a[6] = f2bf(x1.z); a[7] = f2bf(x1.w);
            afrag[ks] = a;
        }
    }
    // g2 for the 4 output rows this lane owns (row = lg*4 + r)
    float g2[4];
    #pragma unroll
    for (int r = 0; r < 4; ++r) g2[r] = e2[target[rowbase + lg * 4 + r]];

    // online-softmax state per (lane, r): covers col slice {l15} of 4 rows
    float m_[4], s_[4], ac_[4];
    #pragma unroll
    for (int r = 0; r < 4; ++r) { m_[r] = -FLT_MAX; s_[r] = 0.f; ac_[r] = 0.f; }

    const int v0base = bx * VCHUNK;

    for (int st = 0; st < NSTEPS; ++st) {
        const int v0 = v0base + st * VSTEP;
        __syncthreads();   // previous iteration's reads done before overwrite
        // ---- stage 16 x 512 fp32 -> bf16 into LDS (swizzled) ----
        #pragma unroll
        for (int p = 0; p < 8; ++p) {
            const int c  = p * 256 + t;      // 8-byte bf16 chunk id, 2048 total
            const int v  = c >> 7;           // 0..15
            const int kq = c & 127;          // 4-float group within row
            f32x4 x = *(const f32x4*)(emb + (size_t)(v0 + v) * DIM + kq * 4);
            bf16x4 b4;
            b4[0] = f2bf(x.x); b4[1] = f2bf(x.y); b4[2] = f2bf(x.z); b4[3] = f2bf(x.w);
            const int inner = (kq * 8) ^ ((v & 7) << 4);
            *(bf16x4*)((char*)ldsb + v * 1024 + inner) = b4;
        }
        __syncthreads();

        // ---- MFMA: dot[16 rows][16 cols], K = 512 ----
        f32x4 acc = {0.f, 0.f, 0.f, 0.f};
        const int swz = (l15 & 7) << 4;
        #pragma unroll
        for (int ks = 0; ks < 16; ++ks) {
            const int inner = (ks * 64 + lg * 16) ^ swz;
            bf16x8 b = *(bf16x8*)((char*)ldsb + l15 * 1024 + inner);
            acc = __builtin_amdgcn_mfma_f32_16x16x32_bf16(afrag[ks], b, acc, 0, 0, 0);
        }

        // ---- fused epilogue: dist -> online softmax accumulate ----
        const float e2v = e2[v0 + l15];
        #pragma unroll
        for (int r = 0; r < 4; ++r) {
            const int rg = rowbase + lg * 4 + r;
            float d2 = g2[r] + e2v - 2.f * acc[r];
            d2 = fmaxf(d2, 0.f);
            const float dist  = sqrtf(fmaxf(d2, 1e-12f));
            const float logit = -dist;
            const float q = -pred_ll[(size_t)rg * VOCAB + (v0 + l15)];
            const float mn = fmaxf(m_[r], logit);
            const float c1 = __expf(m_[r] - mn);
            const float e  = __expf(logit - mn);
            s_[r]  = s_[r]  * c1 + e;
            ac_[r] = ac_[r] * c1 + e * q;
            m_[r]  = mn;
        }
    }

    // ---- combine the 16 col-slices (lanes within each 16-lane group) ----
    #pragma unroll
    for (int r = 0; r < 4; ++r) {
        #pragma unroll
        for (int mask = 1; mask < 16; mask <<= 1) {
            const float mo = __shfl_xor(m_[r], mask);
            const float so = __shfl_xor(s_[r], mask);
            const float ao = __shfl_xor(ac_[r], mask);
            const float mn = fmaxf(m_[r], mo);
            const float c1 = __expf(m_[r] - mn);
            const float c2 = __expf(mo - mn);
            s_[r]  = s_[r]  * c1 + so * c2;
            ac_[r] = ac_[r] * c1 + ao * c2;
            m_[r]  = mn;
        }
        if (l15 == 0) {
            const int rg = rowbase + lg * 4 + r;
            float* pp = partials + ((size_t)rg * NCHUNK + bx) * 3;
            pp[0] = m_[r]; pp[1] = s_[r]; pp[2] = ac_[r];
        }
    }
}

// merge chunk partials per row, gather nll, reduce both scalars
__global__ __launch_bounds__(256) void reduce_kernel(
    const float* __restrict__ pred_ll, const int* __restrict__ target,
    const float* __restrict__ partials, float* __restrict__ out) {
    const int row = blockIdx.x * 256 + threadIdx.x;
    float loss = 0.f, nll = 0.f;
    if (row < NTOK) {
        const int tg = target[row];
        const float mask = (tg != 0) ? 1.f : 0.f;
        const float* pp = partials + (size_t)row * NCHUNK * 3;
        float M = -FLT_MAX;
        #pragma unroll
        for (int c = 0; c < NCHUNK; ++c) M = fmaxf(M, pp[c * 3]);
        float S = 0.f, A = 0.f;
        #pragma unroll
        for (int c = 0; c < NCHUNK; ++c) {
            const float sc = __expf(pp[c * 3] - M);
            S += pp[c * 3 + 1] * sc;
            A += pp[c * 3 + 2] * sc;
        }
        loss = mask * (A / S);
        nll  = mask * (-pred_ll[(size_t)row * VOCAB + tg]);
    }
    #pragma unroll
    for (int o = 32; o > 0; o >>= 1) {
        loss += __shfl_xor(loss, o);
        nll  += __shfl_xor(nll, o);
    }
    if ((threadIdx.x & 63) == 0) {
        atomicAdd(&out[0], loss);
        atomicAdd(&out[1], nll);
    }
}

extern "C" void kernel_launch(void* const* d_in, const int* in_sizes, int n_in,
                              void* d_out, int out_size, void* d_ws, size_t ws_size,
                              hipStream_t stream) {
    const float* pred_ll = (const float*)d_in[0];
    const int*   target  = (const int*)d_in[1];
    const float* emb     = (const float*)d_in[2];
    float* out = (float*)d_out;

    float* e2       = (float*)d_ws;        // VOCAB floats
    float* partials = e2 + VOCAB;          // NTOK*NCHUNK*3 floats

    hipLaunchKernelGGL(init_out, dim3(1), dim3(64), 0, stream, out);
    hipLaunchKernelGGL(e2_kernel, dim3(VOCAB * 64 / 256), dim3(256), 0, stream, emb, e2);
    hipLaunchKernelGGL(fused_kernel, dim3(NCHUNK, NRB), dim3(256), 0, stream,
                       pred_ll, target, emb, e2, partials);
    hipLaunchKernelGGL(reduce_kernel, dim3(NTOK / 256), dim3(256), 0, stream,
                       pred_ll, target, partials, out);
}

// Round 2
// 192.090 us; speedup vs baseline: 2.5746x; 2.5746x over previous
//
#include <hip/hip_runtime.h>
#include <hip/hip_bf16.h>
#include <float.h>

#define NTOK   2048
#define VOCAB  32000
#define DIM    512
#define NCHUNK 40
#define VCHUNK (VOCAB / NCHUNK)   // 800
#define NSTEPS (VCHUNK / 16)      // 50
#define ROWSB  128
#define NRB    (NTOK / ROWSB)     // 16
#define NTILES (VOCAB / 16)       // 2000
#define TILE_BYTES 16384          // 16 rows x 512 k x 2B, swizzled image

typedef __attribute__((ext_vector_type(4))) float  f32x4;
typedef __attribute__((ext_vector_type(8))) short  bf16x8;
typedef unsigned int u32;

__device__ __forceinline__ short f2bf(float f) {
    unsigned u = __builtin_bit_cast(unsigned, f);
    u = (u + 0x7FFFu + ((u >> 16) & 1u)) >> 16;   // RNE to bf16
    return (short)u;
}

__device__ __forceinline__ void async_copy16(void* lds, const void* g) {
    __builtin_amdgcn_global_load_lds(
        (const __attribute__((address_space(1))) u32*)(const u32*)g,
        (__attribute__((address_space(3))) u32*)(u32*)lds, 16, 0, 0);
}

__global__ void init_out(float* out) {
    if (threadIdx.x < 2) out[threadIdx.x] = 0.f;
}

// ---- precast: emb fp32 -> bf16 swizzled tile image + e2, one pass ----
// grid NTILES x 256. Tile = 16 vocab rows. Image byte layout within tile:
//   addr(v, j16) = v*1024 + ((j16*16) ^ ((v&7)<<4)),  j16 = 16B chunk (8 bf16)
__global__ __launch_bounds__(256) void precast_kernel(
    const float* __restrict__ emb, short* __restrict__ Bbf, float* __restrict__ e2) {
    const int tile = blockIdx.x;
    const int t = threadIdx.x, w = t >> 6, l = t & 63;
    const int v0 = tile * 16;
    char* tbase = (char*)Bbf + (size_t)tile * TILE_BYTES;
    #pragma unroll
    for (int it = 0; it < 4; ++it) {
        const int v = it * 4 + w;      // wave w owns row v this iteration
        const int j = l;               // 16B chunk in row, 0..63
        const float* src = emb + (size_t)(v0 + v) * DIM + j * 8;
        f32x4 x0 = *(const f32x4*)src;
        f32x4 x1 = *(const f32x4*)(src + 4);
        bf16x8 b;
        b[0]=f2bf(x0.x); b[1]=f2bf(x0.y); b[2]=f2bf(x0.z); b[3]=f2bf(x0.w);
        b[4]=f2bf(x1.x); b[5]=f2bf(x1.y); b[6]=f2bf(x1.z); b[7]=f2bf(x1.w);
        float sq = x0.x*x0.x + x0.y*x0.y + x0.z*x0.z + x0.w*x0.w
                 + x1.x*x1.x + x1.y*x1.y + x1.z*x1.z + x1.w*x1.w;
        #pragma unroll
        for (int m = 1; m < 64; m <<= 1) sq += __shfl_xor(sq, m);
        if (l == 0) e2[v0 + v] = sq;
        const int addr = v * 1024 + ((j * 16) ^ ((v & 7) << 4));
        *(bf16x8*)(tbase + addr) = b;
    }
}

// e2-only (fallback when ws can't hold Bbf)
__global__ __launch_bounds__(256) void e2_kernel(const float* __restrict__ emb,
                                                 float* __restrict__ e2) {
    int gid = blockIdx.x * 256 + threadIdx.x;
    int wid = gid >> 6, l = gid & 63;
    if (wid >= VOCAB) return;
    const float* row = emb + (size_t)wid * DIM + l * 8;
    f32x4 a = *(const f32x4*)row;
    f32x4 b = *(const f32x4*)(row + 4);
    float s = a.x*a.x + a.y*a.y + a.z*a.z + a.w*a.w
            + b.x*b.x + b.y*b.y + b.z*b.z + b.w*b.w;
    #pragma unroll
    for (int m = 1; m < 64; m <<= 1) s += __shfl_xor(s, m);
    if (l == 0) e2[wid] = s;
}

// ---- fused: MFMA dist -> fixed-max softmax partials ----
// grid (NCHUNK, NRB), 512 threads = 8 waves x 16 rows. Double-buffered B tile.
template<bool PRECAST>
__global__ __launch_bounds__(512, 4) void fused_kernel(
    const float* __restrict__ pred_ll, const int* __restrict__ target,
    const float* __restrict__ emb, const short* __restrict__ Bbf,
    const float* __restrict__ e2g,
    float* __restrict__ partials /* [NTOK][NCHUNK][2] */) {

    const int bx = blockIdx.x;            // v-chunk
    const int by = blockIdx.y;            // row block
    const int t  = threadIdx.x;
    const int w  = t >> 6;                // 0..7
    const int l  = t & 63;
    const int l15 = l & 15;
    const int lg  = l >> 4;               // 0..3

    __shared__ short ldsb[2][16 * DIM];   // 2 x 16KB swizzled B-tile

    const int rowbase = by * ROWSB + w * 16;

    // A fragments: 16 gold rows per wave, reg-resident (fp32 load + convert, once)
    bf16x8 afrag[16];
    {
        const int grow = target[rowbase + l15];
        const float* gsrc = emb + (size_t)grow * DIM;
        #pragma unroll
        for (int ks = 0; ks < 16; ++ks) {
            const int k0 = ks * 32 + lg * 8;
            f32x4 x0 = *(const f32x4*)(gsrc + k0);
            f32x4 x1 = *(const f32x4*)(gsrc + k0 + 4);
            bf16x8 a;
            a[0]=f2bf(x0.x); a[1]=f2bf(x0.y); a[2]=f2bf(x0.z); a[3]=f2bf(x0.w);
            a[4]=f2bf(x1.x); a[5]=f2bf(x1.y); a[6]=f2bf(x1.z); a[7]=f2bf(x1.w);
            afrag[ks] = a;
        }
    }
    float g2[4];
    #pragma unroll
    for (int r = 0; r < 4; ++r) g2[r] = e2g[target[rowbase + lg * 4 + r]];

    float s_[4] = {0.f, 0.f, 0.f, 0.f};
    float ac_[4] = {0.f, 0.f, 0.f, 0.f};

    const int v0base = bx * VCHUNK;
    const int tile0  = v0base >> 4;

    // STAGE tile st into buffer buf
    auto stage = [&](int buf, int st) {
        if constexpr (PRECAST) {
            const char* src = (const char*)Bbf + (size_t)(tile0 + st) * TILE_BYTES;
            char* dst = (char*)&ldsb[buf][0];
            async_copy16(dst + t * 16, src + t * 16);             // 8KB
            async_copy16(dst + 8192 + t * 16, src + 8192 + t * 16); // 8KB
        } else {
            const int v0 = v0base + st * 16;
            #pragma unroll
            for (int it = 0; it < 2; ++it) {
                const int c = it * 512 + t;       // 16B chunk id, 1024 total
                const int v = c >> 6, j = c & 63;
                const float* src = emb + (size_t)(v0 + v) * DIM + j * 8;
                f32x4 x0 = *(const f32x4*)src;
                f32x4 x1 = *(const f32x4*)(src + 4);
                bf16x8 b;
                b[0]=f2bf(x0.x); b[1]=f2bf(x0.y); b[2]=f2bf(x0.z); b[3]=f2bf(x0.w);
                b[4]=f2bf(x1.x); b[5]=f2bf(x1.y); b[6]=f2bf(x1.z); b[7]=f2bf(x1.w);
                const int addr = v * 1024 + ((j * 16) ^ ((v & 7) << 4));
                *(bf16x8*)((char*)&ldsb[buf][0] + addr) = b;
            }
        }
    };

    stage(0, 0);
    __syncthreads();   // drains vmcnt/lgkmcnt: tile 0 resident

    int cur = 0;
    const int swz = (l15 & 7) << 4;
    for (int st = 0; st < NSTEPS; ++st) {
        if (st + 1 < NSTEPS) stage(cur ^ 1, st + 1);

        // prefetch this step's pred_ll slice + e2 (hide HBM latency under MFMA)
        const int v0 = v0base + st * 16;
        const float e2v = e2g[v0 + l15];
        float q[4];
        {
            const size_t p0 = (size_t)(rowbase + lg * 4) * VOCAB + v0 + l15;
            #pragma unroll
            for (int r = 0; r < 4; ++r) q[r] = pred_ll[p0 + (size_t)r * VOCAB];
        }

        // MFMA: 16 rows x 16 cols, K=512
        f32x4 acc = {0.f, 0.f, 0.f, 0.f};
        const char* lb = (const char*)&ldsb[cur][0];
        #pragma unroll
        for (int ks = 0; ks < 16; ++ks) {
            const int inner = (ks * 64 + lg * 16) ^ swz;
            bf16x8 b = *(const bf16x8*)(lb + l15 * 1024 + inner);
            acc = __builtin_amdgcn_mfma_f32_16x16x32_bf16(afrag[ks], b, acc, 0, 0, 0);
        }

        // epilogue: dist -> exp(-dist) accumulate (fixed max = 0, exact)
        #pragma unroll
        for (int r = 0; r < 4; ++r) {
            float d2 = fmaxf(fmaf(-2.f, acc[r], g2[r] + e2v), 1e-12f);
            const float e = __expf(-sqrtf(d2));
            s_[r] += e;
            ac_[r] = fmaf(e, -q[r], ac_[r]);   // accumulates w-weight * (-log p)
        }

        __syncthreads();   // drains staging vmcnt; next buffer ready
        cur ^= 1;
    }

    // combine 16 col-slices within each 16-lane group
    #pragma unroll
    for (int r = 0; r < 4; ++r) {
        float s = s_[r], a = ac_[r];
        #pragma unroll
        for (int m = 1; m < 16; m <<= 1) {
            s += __shfl_xor(s, m);
            a += __shfl_xor(a, m);
        }
        if (l15 == 0) {
            const int rg = rowbase + lg * 4 + r;
            float* pp = partials + ((size_t)rg * NCHUNK + bx) * 2;
            pp[0] = s; pp[1] = a;
        }
    }
}

__global__ __launch_bounds__(256) void reduce_kernel(
    const float* __restrict__ pred_ll, const int* __restrict__ target,
    const float* __restrict__ partials, float* __restrict__ out) {
    const int row = blockIdx.x * 256 + threadIdx.x;
    float loss = 0.f, nll = 0.f;
    if (row < NTOK) {
        const int tg = target[row];
        const float mask = (tg != 0) ? 1.f : 0.f;
        const float* pp = partials + (size_t)row * NCHUNK * 2;
        float S = 0.f, A = 0.f;
        #pragma unroll
        for (int c = 0; c < NCHUNK; ++c) { S += pp[c * 2]; A += pp[c * 2 + 1]; }
        loss = mask * (A / S);
        nll  = mask * (-pred_ll[(size_t)row * VOCAB + tg]);
    }
    #pragma unroll
    for (int o = 32; o > 0; o >>= 1) {
        loss += __shfl_xor(loss, o);
        nll  += __shfl_xor(nll, o);
    }
    if ((threadIdx.x & 63) == 0) {
        atomicAdd(&out[0], loss);
        atomicAdd(&out[1], nll);
    }
}

extern "C" void kernel_launch(void* const* d_in, const int* in_sizes, int n_in,
                              void* d_out, int out_size, void* d_ws, size_t ws_size,
                              hipStream_t stream) {
    const float* pred_ll = (const float*)d_in[0];
    const int*   target  = (const int*)d_in[1];
    const float* emb     = (const float*)d_in[2];
    float* out = (float*)d_out;

    // ws layout: [e2: VOCAB f32][partials: NTOK*NCHUNK*2 f32][Bbf image]
    float* e2       = (float*)d_ws;
    float* partials = e2 + VOCAB;
    const size_t base = (size_t)VOCAB * 4 + (size_t)NTOK * NCHUNK * 2 * 4;
    short* Bbf      = (short*)((char*)d_ws + base);
    const size_t need = base + (size_t)NTILES * TILE_BYTES;
    const bool precast = (ws_size >= need);

    hipLaunchKernelGGL(init_out, dim3(1), dim3(64), 0, stream, out);
    if (precast) {
        hipLaunchKernelGGL(precast_kernel, dim3(NTILES), dim3(256), 0, stream, emb, Bbf, e2);
        hipLaunchKernelGGL((fused_kernel<true>), dim3(NCHUNK, NRB), dim3(512), 0, stream,
                           pred_ll, target, emb, Bbf, e2, partials);
    } else {
        hipLaunchKernelGGL(e2_kernel, dim3(VOCAB * 64 / 256), dim3(256), 0, stream, emb, e2);
        hipLaunchKernelGGL((fused_kernel<false>), dim3(NCHUNK, NRB), dim3(512), 0, stream,
                           pred_ll, target, emb, Bbf, e2, partials);
    }
    hipLaunchKernelGGL(reduce_kernel, dim3(NTOK / 256), dim3(256), 0, stream,
                       pred_ll, target, partials, out);
}

// Round 3
// 180.359 us; speedup vs baseline: 2.7421x; 1.0650x over previous
//
#include <hip/hip_runtime.h>
#include <hip/hip_bf16.h>
#include <float.h>

#define NTOK   2048
#define VOCAB  32000
#define DIM    512
#define NCHUNK 128
#define NTILES 2000               // 16-row vocab tiles
#define ROWSB  256                // rows per block (8 waves x 32 rows)
#define NRB    (NTOK / ROWSB)     // 8
#define TILE_BYTES 16384          // 16 rows x 512 k x 2B, swizzled image

typedef __attribute__((ext_vector_type(4))) float  f32x4;
typedef __attribute__((ext_vector_type(8))) short  bf16x8;
typedef unsigned int u32;

__device__ __forceinline__ short f2bf(float f) {
    unsigned u = __builtin_bit_cast(unsigned, f);
    u = (u + 0x7FFFu + ((u >> 16) & 1u)) >> 16;   // RNE to bf16
    return (short)u;
}

__device__ __forceinline__ void async_copy16(void* lds, const void* g) {
    __builtin_amdgcn_global_load_lds(
        (const __attribute__((address_space(1))) u32*)(const u32*)g,
        (__attribute__((address_space(3))) u32*)(u32*)lds, 16, 0, 0);
}

__global__ void init_out(float* out) {
    if (threadIdx.x < 2) out[threadIdx.x] = 0.f;
}

// ---- precast: emb fp32 -> bf16 swizzled tile image + e2, one pass ----
// addr(v, j16) = v*1024 + ((j16*16) ^ ((v&7)<<4)), j16 = 16B chunk (8 bf16)
__global__ __launch_bounds__(256) void precast_kernel(
    const float* __restrict__ emb, short* __restrict__ Bbf, float* __restrict__ e2) {
    const int tile = blockIdx.x;
    const int t = threadIdx.x, w = t >> 6, l = t & 63;
    const int v0 = tile * 16;
    char* tbase = (char*)Bbf + (size_t)tile * TILE_BYTES;
    #pragma unroll
    for (int it = 0; it < 4; ++it) {
        const int v = it * 4 + w;
        const int j = l;
        const float* src = emb + (size_t)(v0 + v) * DIM + j * 8;
        f32x4 x0 = *(const f32x4*)src;
        f32x4 x1 = *(const f32x4*)(src + 4);
        bf16x8 b;
        b[0]=f2bf(x0.x); b[1]=f2bf(x0.y); b[2]=f2bf(x0.z); b[3]=f2bf(x0.w);
        b[4]=f2bf(x1.x); b[5]=f2bf(x1.y); b[6]=f2bf(x1.z); b[7]=f2bf(x1.w);
        float sq = x0.x*x0.x + x0.y*x0.y + x0.z*x0.z + x0.w*x0.w
                 + x1.x*x1.x + x1.y*x1.y + x1.z*x1.z + x1.w*x1.w;
        #pragma unroll
        for (int m = 1; m < 64; m <<= 1) sq += __shfl_xor(sq, m);
        if (l == 0) e2[v0 + v] = sq;
        const int addr = v * 1024 + ((j * 16) ^ ((v & 7) << 4));
        *(bf16x8*)(tbase + addr) = b;
    }
}

__global__ __launch_bounds__(256) void e2_kernel(const float* __restrict__ emb,
                                                 float* __restrict__ e2) {
    int gid = blockIdx.x * 256 + threadIdx.x;
    int wid = gid >> 6, l = gid & 63;
    if (wid >= VOCAB) return;
    const float* row = emb + (size_t)wid * DIM + l * 8;
    f32x4 a = *(const f32x4*)row;
    f32x4 b = *(const f32x4*)(row + 4);
    float s = a.x*a.x + a.y*a.y + a.z*a.z + a.w*a.w
            + b.x*b.x + b.y*b.y + b.z*b.z + b.w*b.w;
    #pragma unroll
    for (int m = 1; m < 64; m <<= 1) s += __shfl_xor(s, m);
    if (l == 0) e2[wid] = s;
}

// ---- fused: 8 waves x 32 rows/wave = 256 rows/block; double-buffered tiles ----
// grid (NRB, NCHUNK): x = row-block (fast) so chunk-sharing blocks co-dispatch
template<bool PRECAST>
__global__ __launch_bounds__(512, 2) void fused_kernel(
    const float* __restrict__ pred_ll, const int* __restrict__ target,
    const float* __restrict__ emb, const short* __restrict__ Bbf,
    const float* __restrict__ e2g,
    float* __restrict__ partials /* [NTOK][NCHUNK][2] */) {

    const int rb = blockIdx.x;
    const int ch = blockIdx.y;
    const int t  = threadIdx.x;
    const int w  = t >> 6;                // 0..7
    const int l  = t & 63;
    const int l15 = l & 15;
    const int lg  = l >> 4;               // 0..3

    __shared__ short ldsb[2][16 * DIM];   // 2 x 16KB swizzled B-tile

    const int t0 = (ch * NTILES) >> 7;    // chunk tile range [t0, t1)
    const int t1 = ((ch + 1) * NTILES) >> 7;
    const int rowbase = rb * ROWSB + w * 32;

    // A fragments: 32 gold rows per wave (2 sets of 16), bf16-gathered
    bf16x8 afrag[2][16];
    #pragma unroll
    for (int s = 0; s < 2; ++s) {
        const int grow = target[rowbase + s * 16 + l15];
        if constexpr (PRECAST) {
            const char* abase = (const char*)Bbf + (size_t)(grow >> 4) * TILE_BYTES
                              + (grow & 15) * 1024;
            const int aswz = (grow & 7) << 4;
            #pragma unroll
            for (int ks = 0; ks < 16; ++ks)
                afrag[s][ks] = *(const bf16x8*)(abase + (((ks * 4 + lg) * 16) ^ aswz));
        } else {
            const float* gsrc = emb + (size_t)grow * DIM;
            #pragma unroll
            for (int ks = 0; ks < 16; ++ks) {
                const int k0 = ks * 32 + lg * 8;
                f32x4 x0 = *(const f32x4*)(gsrc + k0);
                f32x4 x1 = *(const f32x4*)(gsrc + k0 + 4);
                bf16x8 a;
                a[0]=f2bf(x0.x); a[1]=f2bf(x0.y); a[2]=f2bf(x0.z); a[3]=f2bf(x0.w);
                a[4]=f2bf(x1.x); a[5]=f2bf(x1.y); a[6]=f2bf(x1.z); a[7]=f2bf(x1.w);
                afrag[s][ks] = a;
            }
        }
    }
    float g2[2][4];
    #pragma unroll
    for (int s = 0; s < 2; ++s)
        #pragma unroll
        for (int r = 0; r < 4; ++r)
            g2[s][r] = e2g[target[rowbase + s * 16 + lg * 4 + r]];

    float s_[2][4] = {{0,0,0,0},{0,0,0,0}};
    float ac_[2][4] = {{0,0,0,0},{0,0,0,0}};

    auto stage = [&](int buf, int tg) {
        if constexpr (PRECAST) {
            const char* src = (const char*)Bbf + (size_t)tg * TILE_BYTES;
            char* dst = (char*)&ldsb[buf][0];
            async_copy16(dst + t * 16, src + t * 16);               // 8KB
            async_copy16(dst + 8192 + t * 16, src + 8192 + t * 16); // 8KB
        } else {
            const int v0 = tg * 16;
            #pragma unroll
            for (int it = 0; it < 2; ++it) {
                const int c = it * 512 + t;
                const int v = c >> 6, j = c & 63;
                const float* src = emb + (size_t)(v0 + v) * DIM + j * 8;
                f32x4 x0 = *(const f32x4*)src;
                f32x4 x1 = *(const f32x4*)(src + 4);
                bf16x8 b;
                b[0]=f2bf(x0.x); b[1]=f2bf(x0.y); b[2]=f2bf(x0.z); b[3]=f2bf(x0.w);
                b[4]=f2bf(x1.x); b[5]=f2bf(x1.y); b[6]=f2bf(x1.z); b[7]=f2bf(x1.w);
                const int addr = v * 1024 + ((j * 16) ^ ((v & 7) << 4));
                *(bf16x8*)((char*)&ldsb[buf][0] + addr) = b;
            }
        }
    };

    stage(0, t0);
    __syncthreads();

    int cur = 0;
    const int swz = (l15 & 7) << 4;
    for (int tg = t0; tg < t1; ++tg) {
        if (tg + 1 < t1) stage(cur ^ 1, tg + 1);

        const int v0 = tg * 16;
        const float e2v = e2g[v0 + l15];
        float q[2][4];
        {
            const size_t p0 = (size_t)rowbase * VOCAB + v0 + l15;
            #pragma unroll
            for (int s = 0; s < 2; ++s)
                #pragma unroll
                for (int r = 0; r < 4; ++r)
                    q[s][r] = pred_ll[p0 + (size_t)(s * 16 + lg * 4 + r) * VOCAB];
        }

        // MFMA: 32 rows x 16 cols, K=512 — each B-read feeds 2 MFMAs
        f32x4 accs[2] = {{0,0,0,0},{0,0,0,0}};
        const char* lb = (const char*)&ldsb[cur][0];
        #pragma unroll
        for (int ks = 0; ks < 16; ++ks) {
            const int inner = (ks * 64 + lg * 16) ^ swz;
            bf16x8 b = *(const bf16x8*)(lb + l15 * 1024 + inner);
            accs[0] = __builtin_amdgcn_mfma_f32_16x16x32_bf16(afrag[0][ks], b, accs[0], 0, 0, 0);
            accs[1] = __builtin_amdgcn_mfma_f32_16x16x32_bf16(afrag[1][ks], b, accs[1], 0, 0, 0);
        }

        // epilogue: dist -> exp(-dist), fixed max = 0 (exact: dist >= 0)
        #pragma unroll
        for (int s = 0; s < 2; ++s)
            #pragma unroll
            for (int r = 0; r < 4; ++r) {
                float d2 = fmaxf(fmaf(-2.f, accs[s][r], g2[s][r] + e2v), 1e-12f);
                const float e = __expf(-sqrtf(d2));
                s_[s][r] += e;
                ac_[s][r] = fmaf(e, -q[s][r], ac_[s][r]);
            }

        __syncthreads();
        cur ^= 1;
    }

    // combine 16 col-slices within each 16-lane group
    #pragma unroll
    for (int s = 0; s < 2; ++s)
        #pragma unroll
        for (int r = 0; r < 4; ++r) {
            float sv = s_[s][r], av = ac_[s][r];
            #pragma unroll
            for (int m = 1; m < 16; m <<= 1) {
                sv += __shfl_xor(sv, m);
                av += __shfl_xor(av, m);
            }
            if (l15 == 0) {
                const int rg = rowbase + s * 16 + lg * 4 + r;
                float* pp = partials + ((size_t)rg * NCHUNK + ch) * 2;
                pp[0] = sv; pp[1] = av;
            }
        }
}

__global__ __launch_bounds__(256) void reduce_kernel(
    const float* __restrict__ pred_ll, const int* __restrict__ target,
    const float* __restrict__ partials, float* __restrict__ out) {
    const int row = blockIdx.x * 256 + threadIdx.x;
    float loss = 0.f, nll = 0.f;
    if (row < NTOK) {
        const int tg = target[row];
        const float mask = (tg != 0) ? 1.f : 0.f;
        const float* pp = partials + (size_t)row * NCHUNK * 2;
        float S = 0.f, A = 0.f;
        #pragma unroll 8
        for (int c = 0; c < NCHUNK; ++c) { S += pp[c * 2]; A += pp[c * 2 + 1]; }
        loss = mask * (A / S);
        nll  = mask * (-pred_ll[(size_t)row * VOCAB + tg]);
    }
    #pragma unroll
    for (int o = 32; o > 0; o >>= 1) {
        loss += __shfl_xor(loss, o);
        nll  += __shfl_xor(nll, o);
    }
    if ((threadIdx.x & 63) == 0) {
        atomicAdd(&out[0], loss);
        atomicAdd(&out[1], nll);
    }
}

extern "C" void kernel_launch(void* const* d_in, const int* in_sizes, int n_in,
                              void* d_out, int out_size, void* d_ws, size_t ws_size,
                              hipStream_t stream) {
    const float* pred_ll = (const float*)d_in[0];
    const int*   target  = (const int*)d_in[1];
    const float* emb     = (const float*)d_in[2];
    float* out = (float*)d_out;

    // ws layout: [e2: VOCAB f32][partials: NTOK*NCHUNK*2 f32][Bbf image]
    float* e2       = (float*)d_ws;
    float* partials = e2 + VOCAB;
    const size_t base = (size_t)VOCAB * 4 + (size_t)NTOK * NCHUNK * 2 * 4;
    short* Bbf      = (short*)((char*)d_ws + base);
    const size_t need = base + (size_t)NTILES * TILE_BYTES;
    const bool precast = (ws_size >= need);

    hipLaunchKernelGGL(init_out, dim3(1), dim3(64), 0, stream, out);
    if (precast) {
        hipLaunchKernelGGL(precast_kernel, dim3(NTILES), dim3(256), 0, stream, emb, Bbf, e2);
        hipLaunchKernelGGL((fused_kernel<true>), dim3(NRB, NCHUNK), dim3(512), 0, stream,
                           pred_ll, target, emb, Bbf, e2, partials);
    } else {
        hipLaunchKernelGGL(e2_kernel, dim3(VOCAB * 64 / 256), dim3(256), 0, stream, emb, e2);
        hipLaunchKernelGGL((fused_kernel<false>), dim3(NRB, NCHUNK), dim3(512), 0, stream,
                           pred_ll, target, emb, Bbf, e2, partials);
    }
    hipLaunchKernelGGL(reduce_kernel, dim3(NTOK / 256), dim3(256), 0, stream,
                       pred_ll, target, partials, out);
}

// Round 4
// 179.598 us; speedup vs baseline: 2.7537x; 1.0042x over previous
//
#include <hip/hip_runtime.h>
#include <hip/hip_bf16.h>
#include <float.h>

#define NTOK   2048
#define VOCAB  32000
#define DIM    512
#define NCHUNK 128
#define NTILES 2000               // 16-row vocab tiles
#define ROWSB  128                // rows per block (4 waves x 32 rows)
#define NRB    (NTOK / ROWSB)     // 16
#define TILE_BYTES 16384          // 16 rows x 512 k x 2B, swizzled image
#define QTILE_BYTES 8192          // 128 rows x 16 cols x 4B, window-XOR image

typedef __attribute__((ext_vector_type(4))) float  f32x4;
typedef __attribute__((ext_vector_type(8))) short  bf16x8;
typedef unsigned int u32;

__device__ __forceinline__ short f2bf(float f) {
    unsigned u = __builtin_bit_cast(unsigned, f);
    u = (u + 0x7FFFu + ((u >> 16) & 1u)) >> 16;   // RNE to bf16
    return (short)u;
}

__device__ __forceinline__ void async_copy16(void* lds, const void* g) {
    __builtin_amdgcn_global_load_lds(
        (const __attribute__((address_space(1))) u32*)(const u32*)g,
        (__attribute__((address_space(3))) u32*)(u32*)lds, 16, 0, 0);
}

// q image XOR: spread the 64B row window across both 16-bank halves by row bit2
__device__ __forceinline__ int qswz(int addr) {
    return addr ^ (((addr >> 8) & 1) << 6);   // involution
}

__global__ void init_out(float* out) {
    if (threadIdx.x < 2) out[threadIdx.x] = 0.f;
}

// ---- precast: emb fp32 -> bf16 swizzled tile image + e2, one pass ----
// addr(v, j16) = v*1024 + ((j16*16) ^ ((v&7)<<4)), j16 = 16B chunk (8 bf16)
__global__ __launch_bounds__(256) void precast_kernel(
    const float* __restrict__ emb, short* __restrict__ Bbf, float* __restrict__ e2) {
    const int tile = blockIdx.x;
    const int t = threadIdx.x, w = t >> 6, l = t & 63;
    const int v0 = tile * 16;
    char* tbase = (char*)Bbf + (size_t)tile * TILE_BYTES;
    #pragma unroll
    for (int it = 0; it < 4; ++it) {
        const int v = it * 4 + w;
        const int j = l;
        const float* src = emb + (size_t)(v0 + v) * DIM + j * 8;
        f32x4 x0 = *(const f32x4*)src;
        f32x4 x1 = *(const f32x4*)(src + 4);
        bf16x8 b;
        b[0]=f2bf(x0.x); b[1]=f2bf(x0.y); b[2]=f2bf(x0.z); b[3]=f2bf(x0.w);
        b[4]=f2bf(x1.x); b[5]=f2bf(x1.y); b[6]=f2bf(x1.z); b[7]=f2bf(x1.w);
        float sq = x0.x*x0.x + x0.y*x0.y + x0.z*x0.z + x0.w*x0.w
                 + x1.x*x1.x + x1.y*x1.y + x1.z*x1.z + x1.w*x1.w;
        #pragma unroll
        for (int m = 1; m < 64; m <<= 1) sq += __shfl_xor(sq, m);
        if (l == 0) e2[v0 + v] = sq;
        const int addr = v * 1024 + ((j * 16) ^ ((v & 7) << 4));
        *(bf16x8*)(tbase + addr) = b;
    }
}

__global__ __launch_bounds__(256) void e2_kernel(const float* __restrict__ emb,
                                                 float* __restrict__ e2) {
    int gid = blockIdx.x * 256 + threadIdx.x;
    int wid = gid >> 6, l = gid & 63;
    if (wid >= VOCAB) return;
    const float* row = emb + (size_t)wid * DIM + l * 8;
    f32x4 a = *(const f32x4*)row;
    f32x4 b = *(const f32x4*)(row + 4);
    float s = a.x*a.x + a.y*a.y + a.z*a.z + a.w*a.w
            + b.x*b.x + b.y*b.y + b.z*b.z + b.w*b.w;
    #pragma unroll
    for (int m = 1; m < 64; m <<= 1) s += __shfl_xor(s, m);
    if (l == 0) e2[wid] = s;
}

// ---- fused: 4 waves x 32 rows = 128 rows/block; B+q double-buffered async ----
template<bool PRECAST>
__global__ __launch_bounds__(256, 2) void fused_kernel(
    const float* __restrict__ pred_ll, const int* __restrict__ target,
    const float* __restrict__ emb, const short* __restrict__ Bbf,
    const float* __restrict__ e2g,
    float* __restrict__ partials /* [NTOK][NCHUNK][2] */) {

    const int rb = blockIdx.x;
    const int ch = blockIdx.y;
    const int t  = threadIdx.x;
    const int w  = t >> 6;                // 0..3
    const int l  = t & 63;
    const int l15 = l & 15;
    const int lg  = l >> 4;               // 0..3

    __shared__ char ldsB[2][TILE_BYTES];   // swizzled B tiles
    __shared__ char ldsQ[2][QTILE_BYTES];  // window-XOR q tiles

    const int t0 = (ch * NTILES) >> 7;
    const int t1 = ((ch + 1) * NTILES) >> 7;
    const int rowblk = rb * ROWSB;
    const int rowbase = rowblk + w * 32;

    // A fragments: 32 gold rows per wave (2 sets of 16)
    bf16x8 afrag[2][16];
    #pragma unroll
    for (int s = 0; s < 2; ++s) {
        const int grow = target[rowbase + s * 16 + l15];
        if constexpr (PRECAST) {
            const char* abase = (const char*)Bbf + (size_t)(grow >> 4) * TILE_BYTES
                              + (grow & 15) * 1024;
            const int aswz = (grow & 7) << 4;
            #pragma unroll
            for (int ks = 0; ks < 16; ++ks)
                afrag[s][ks] = *(const bf16x8*)(abase + (((ks * 4 + lg) * 16) ^ aswz));
        } else {
            const float* gsrc = emb + (size_t)grow * DIM;
            #pragma unroll
            for (int ks = 0; ks < 16; ++ks) {
                const int k0 = ks * 32 + lg * 8;
                f32x4 x0 = *(const f32x4*)(gsrc + k0);
                f32x4 x1 = *(const f32x4*)(gsrc + k0 + 4);
                bf16x8 a;
                a[0]=f2bf(x0.x); a[1]=f2bf(x0.y); a[2]=f2bf(x0.z); a[3]=f2bf(x0.w);
                a[4]=f2bf(x1.x); a[5]=f2bf(x1.y); a[6]=f2bf(x1.z); a[7]=f2bf(x1.w);
                afrag[s][ks] = a;
            }
        }
    }
    float g2[2][4];
    #pragma unroll
    for (int s = 0; s < 2; ++s)
        #pragma unroll
        for (int r = 0; r < 4; ++r)
            g2[s][r] = e2g[target[rowbase + s * 16 + lg * 4 + r]];

    float s_[2][4] = {{0,0,0,0},{0,0,0,0}};
    float ac_[2][4] = {{0,0,0,0},{0,0,0,0}};

    // stage B tile (16KB linear copy of swizzled image) + q tile (8KB, XOR map)
    auto stage = [&](int buf, int tg) {
        const int v0 = tg * 16;
        if constexpr (PRECAST) {
            const char* srcB = (const char*)Bbf + (size_t)tg * TILE_BYTES;
            char* dstB = ldsB[buf];
            #pragma unroll
            for (int it = 0; it < 4; ++it)
                async_copy16(dstB + it * 4096 + t * 16, srcB + it * 4096 + t * 16);
        } else {
            #pragma unroll
            for (int it = 0; it < 2; ++it) {
                const int c = it * 256 + t;          // 512 x 32B? -> 16 rows x 512k
                const int v = c >> 5, j = c & 31;    // j: 32B chunk (16 bf16)
                const float* src = emb + (size_t)(v0 + v) * DIM + j * 16;
                f32x4 x0 = *(const f32x4*)src;
                f32x4 x1 = *(const f32x4*)(src + 4);
                f32x4 x2 = *(const f32x4*)(src + 8);
                f32x4 x3 = *(const f32x4*)(src + 12);
                bf16x8 b0, b1;
                b0[0]=f2bf(x0.x); b0[1]=f2bf(x0.y); b0[2]=f2bf(x0.z); b0[3]=f2bf(x0.w);
                b0[4]=f2bf(x1.x); b0[5]=f2bf(x1.y); b0[6]=f2bf(x1.z); b0[7]=f2bf(x1.w);
                b1[0]=f2bf(x2.x); b1[1]=f2bf(x2.y); b1[2]=f2bf(x2.z); b1[3]=f2bf(x2.w);
                b1[4]=f2bf(x3.x); b1[5]=f2bf(x3.y); b1[6]=f2bf(x3.z); b1[7]=f2bf(x3.w);
                const int a0 = v * 1024 + (((j * 2    ) * 16) ^ ((v & 7) << 4));
                const int a1 = v * 1024 + (((j * 2 + 1) * 16) ^ ((v & 7) << 4));
                *(bf16x8*)(ldsB[buf] + a0) = b0;
                *(bf16x8*)(ldsB[buf] + a1) = b1;
            }
        }
        // q: 128 rows x 64B, image offset p holds global chunk qswz(p)
        char* dstQ = ldsQ[buf];
        #pragma unroll
        for (int it = 0; it < 2; ++it) {
            const int p = (it * 256 + t) * 16;
            const int a = qswz(p);
            const int row = a >> 6, c16 = (a >> 4) & 3;
            const float* src = pred_ll + (size_t)(rowblk + row) * VOCAB + v0 + c16 * 4;
            async_copy16(dstQ + p, src);
        }
    };

    stage(0, t0);

    int cur = 0;
    const int swz = (l15 & 7) << 4;
    for (int tg = t0; tg < t1; ++tg) {
        if (tg + 1 < t1) {
            stage(cur ^ 1, tg + 1);
            if constexpr (PRECAST)
                asm volatile("s_waitcnt vmcnt(6)" ::: "memory");
            else
                asm volatile("s_waitcnt vmcnt(2) lgkmcnt(0)" ::: "memory");
        } else {
            asm volatile("s_waitcnt vmcnt(0) lgkmcnt(0)" ::: "memory");
        }
        __builtin_amdgcn_s_barrier();

        const int v0 = tg * 16;
        const float e2v = e2g[v0 + l15];

        // MFMA: 32 rows x 16 cols, K=512
        f32x4 accs[2] = {{0,0,0,0},{0,0,0,0}};
        const char* lb = ldsB[cur];
        #pragma unroll
        for (int ks = 0; ks < 16; ++ks) {
            const int inner = (ks * 64 + lg * 16) ^ swz;
            bf16x8 b = *(const bf16x8*)(lb + l15 * 1024 + inner);
            accs[0] = __builtin_amdgcn_mfma_f32_16x16x32_bf16(afrag[0][ks], b, accs[0], 0, 0, 0);
            accs[1] = __builtin_amdgcn_mfma_f32_16x16x32_bf16(afrag[1][ks], b, accs[1], 0, 0, 0);
        }

        // epilogue: q from LDS, dist -> exp(-dist) (fixed max = 0, exact)
        const char* lq = ldsQ[cur];
        #pragma unroll
        for (int s = 0; s < 2; ++s)
            #pragma unroll
            for (int r = 0; r < 4; ++r) {
                const int rloc = w * 32 + s * 16 + lg * 4 + r;
                const float q = *(const float*)(lq + qswz(rloc * 64 + l15 * 4));
                float d2 = fmaxf(fmaf(-2.f, accs[s][r], g2[s][r] + e2v), 1e-12f);
                const float e = __expf(-sqrtf(d2));
                s_[s][r] += e;
                ac_[s][r] = fmaf(e, -q, ac_[s][r]);
            }

        asm volatile("" ::: "memory");
        __builtin_amdgcn_s_barrier();   // reads done before next overwrite
        cur ^= 1;
    }

    // combine 16 col-slices within each 16-lane group
    #pragma unroll
    for (int s = 0; s < 2; ++s)
        #pragma unroll
        for (int r = 0; r < 4; ++r) {
            float sv = s_[s][r], av = ac_[s][r];
            #pragma unroll
            for (int m = 1; m < 16; m <<= 1) {
                sv += __shfl_xor(sv, m);
                av += __shfl_xor(av, m);
            }
            if (l15 == 0) {
                const int rg = rowbase + s * 16 + lg * 4 + r;
                float* pp = partials + ((size_t)rg * NCHUNK + ch) * 2;
                pp[0] = sv; pp[1] = av;
            }
        }
}

__global__ __launch_bounds__(256) void reduce_kernel(
    const float* __restrict__ pred_ll, const int* __restrict__ target,
    const float* __restrict__ partials, float* __restrict__ out) {
    const int row = blockIdx.x * 256 + threadIdx.x;
    float loss = 0.f, nll = 0.f;
    if (row < NTOK) {
        const int tg = target[row];
        const float mask = (tg != 0) ? 1.f : 0.f;
        const float* pp = partials + (size_t)row * NCHUNK * 2;
        float S = 0.f, A = 0.f;
        #pragma unroll 8
        for (int c = 0; c < NCHUNK; ++c) { S += pp[c * 2]; A += pp[c * 2 + 1]; }
        loss = mask * (A / S);
        nll  = mask * (-pred_ll[(size_t)row * VOCAB + tg]);
    }
    #pragma unroll
    for (int o = 32; o > 0; o >>= 1) {
        loss += __shfl_xor(loss, o);
        nll  += __shfl_xor(nll, o);
    }
    if ((threadIdx.x & 63) == 0) {
        atomicAdd(&out[0], loss);
        atomicAdd(&out[1], nll);
    }
}

extern "C" void kernel_launch(void* const* d_in, const int* in_sizes, int n_in,
                              void* d_out, int out_size, void* d_ws, size_t ws_size,
                              hipStream_t stream) {
    const float* pred_ll = (const float*)d_in[0];
    const int*   target  = (const int*)d_in[1];
    const float* emb     = (const float*)d_in[2];
    float* out = (float*)d_out;

    // ws layout: [e2: VOCAB f32][partials: NTOK*NCHUNK*2 f32][Bbf image]
    float* e2       = (float*)d_ws;
    float* partials = e2 + VOCAB;
    const size_t base = (size_t)VOCAB * 4 + (size_t)NTOK * NCHUNK * 2 * 4;
    short* Bbf      = (short*)((char*)d_ws + base);
    const size_t need = base + (size_t)NTILES * TILE_BYTES;
    const bool precast = (ws_size >= need);

    hipLaunchKernelGGL(init_out, dim3(1), dim3(64), 0, stream, out);
    if (precast) {
        hipLaunchKernelGGL(precast_kernel, dim3(NTILES), dim3(256), 0, stream, emb, Bbf, e2);
        hipLaunchKernelGGL((fused_kernel<true>), dim3(NRB, NCHUNK), dim3(256), 0, stream,
                           pred_ll, target, emb, Bbf, e2, partials);
    } else {
        hipLaunchKernelGGL(e2_kernel, dim3(VOCAB * 64 / 256), dim3(256), 0, stream, emb, e2);
        hipLaunchKernelGGL((fused_kernel<false>), dim3(NRB, NCHUNK), dim3(256), 0, stream,
                           pred_ll, target, emb, Bbf, e2, partials);
    }
    hipLaunchKernelGGL(reduce_kernel, dim3(NTOK / 256), dim3(256), 0, stream,
                       pred_ll, target, partials, out);
}